// Round 7
// baseline (462.537 us; speedup 1.0000x reference)
//
#include <hip/hip_runtime.h>

#define B_    8192
#define N_    29
#define F_    147
#define DC    429
#define D_    128
#define ROWS  (B_*N_)
#define EPSBN 1e-5f

#define UTSTR   4096                        /* shorts per b */
#define RS_SH   3712                        /* short offset of rowstats */

/* ws layout in float units */
#define X3_OFF   16777216                   /* fp32 B_*128 */
#define ACC_OFF  (X3_OFF + B_*D_)
#define BN1_OFF  (ACC_OFF)                  /* 32*29*2 */
#define BN2_OFF  (ACC_OFF + 1856)
#define BN3_OFF  (ACC_OFF + 3712)           /* 32*128*2 */
#define FIN_OFF  (ACC_OFF + 11904)
/* FIN_OFF+0..28: m1s (k2 out), FIN_OFF+32..60: is1s (k2 out) */
#define CSW_OFF  (FIN_OFF + 384)
#define V_OFF    (FIN_OFF + 512)
#define V1_OFF   (FIN_OFF + 640)
#define CSWP_OFF (FIN_OFF + 768)
#define IMG_OFF  (FIN_OFF + 1024)           /* bf16 Wg image: 128*448 shorts */
#define WPI_OFF  (IMG_OFF + 28672)          /* bf16 Wp^T image: 128*128 shorts */
#define WM1I_OFF (WPI_OFF + 8192)           /* bf16 Wm1^T image */

typedef __bf16 bf16x8 __attribute__((ext_vector_type(8)));
typedef float  f32x4  __attribute__((ext_vector_type(4)));
typedef float  f32x2  __attribute__((ext_vector_type(2)));

__device__ __forceinline__ unsigned short f2bf(float f) {
  __bf16 h = (__bf16)f;
  return __builtin_bit_cast(unsigned short, h);
}
__device__ __forceinline__ float bf2f(unsigned u16) {
  return __uint_as_float(u16 << 16);
}
__device__ __forceinline__ unsigned packbf(f32x2 v) {
  return (unsigned)f2bf(v[0]) | ((unsigned)f2bf(v[1]) << 16);
}
__device__ __forceinline__ f32x2 pfma(f32x2 a, float s, f32x2 c) {
  return __builtin_elementwise_fma(a, (f32x2){s, s}, c);
}
__device__ __forceinline__ f32x2 prelu2(f32x2 v, float a) {
  f32x2 z = (f32x2){0.f, 0.f};
  return __builtin_elementwise_fma(__builtin_elementwise_min(v, z), (f32x2){a, a},
                                   __builtin_elementwise_max(v, z));
}
__device__ __forceinline__ void gload_lds4(const float* g, void* l) {
  __builtin_amdgcn_global_load_lds((const __attribute__((address_space(1))) void*)g,
                                   (__attribute__((address_space(3))) void*)l, 4, 0, 0);
}

#define TSTR 456
#define UTILS 34
#define ATSTR 136  /* k4/k5 A-tile stride (shorts) */
#define KB4 16     /* batches per k4/k5 block */

/* K0: Wg image + colsum (blocks 0..15); Wp^T image + colsum (16); Wm1^T image (17);
   centroid vector + V1 + ACC zero (18). */
__global__ void k0_setup(const float* __restrict__ Wg, const float* __restrict__ Wp,
                         const float* __restrict__ Wm1, const float* __restrict__ cent,
                         const float* __restrict__ hw, float* __restrict__ ws)
{
  const int tid = threadIdx.x;
  if (blockIdx.x < 16) {
    __shared__ float cs_l[8];
    const int kb = blockIdx.x * 8;
    if (tid < 8) cs_l[tid] = 0.f;
    __syncthreads();
    unsigned short* img = (unsigned short*)(ws + IMG_OFF);
    for (int i = tid; i < 8*448; i += 256) {
      int kk = i / 448, dk = i - kk*448;
      int k = kb + kk;
      int d;
      if      (dk < 145)  d = dk;
      else if (dk == 145) d = -1;
      else if (dk < 289)  d = dk - 1;
      else if (dk == 289) d = -1;
      else if (dk < 431)  d = dk - 2;
      else                d = -1;
      float v = (d >= 0) ? Wg[(size_t)d*D_ + k] : 0.f;
      img[(size_t)k*448 + dk] = f2bf(v);
      if (d >= 0) atomicAdd(&cs_l[kk], v);
    }
    __syncthreads();
    if (tid < 8) ws[CSW_OFF + kb + tid] = cs_l[tid];
  } else if (blockIdx.x == 16) {
    unsigned short* wpi = (unsigned short*)(ws + WPI_OFF);
    for (int i = tid; i < 16384; i += 256) {
      int k = i >> 7, c = i & 127;
      wpi[c*128 + k] = f2bf(Wp[k*128 + c]);
    }
    if (tid < 128) {
      float s = 0.f;
      for (int k = 0; k < 128; ++k) s += Wp[k*128 + tid];
      ws[CSWP_OFF + tid] = s;
    }
  } else if (blockIdx.x == 17) {
    unsigned short* wmi = (unsigned short*)(ws + WM1I_OFF);
    for (int i = tid; i < 16384; i += 256) {
      int k = i >> 7, c = i & 127;
      wmi[c*128 + k] = f2bf(Wm1[k*128 + c]);
    }
  } else {
    const int wv = tid >> 6, lane = tid & 63;
    if (wv == 0) {
      float vk0 = 0.f, vk1 = 0.f;
      for (int h = 0; h < 4; ++h) {
        float c0 = cent[h*D_ + lane];
        float c1 = cent[h*D_ + 64 + lane];
        float s = c0*c0 + c1*c1;
        #pragma unroll
        for (int off = 32; off >= 1; off >>= 1) s += __shfl_xor(s, off);
        float w = hw[h] / (sqrtf(s) + 1e-8f);
        vk0 = fmaf(c0, w, vk0);
        vk1 = fmaf(c1, w, vk1);
      }
      ws[V_OFF + lane]      = vk0;
      ws[V_OFF + 64 + lane] = vk1;
      float t = vk0 + vk1;
      #pragma unroll
      for (int off = 32; off >= 1; off >>= 1) t += __shfl_xor(t, off);
      if (lane == 0) ws[V1_OFF] = t;
    } else {
      for (int i = tid - 64; i < 11904; i += 192) ws[ACC_OFF + i] = 0.f;
    }
  }
}

/* K1: 1 b per block, 256 threads, LDS 29,184 B -> 5 blocks/CU.
   Launched as TWO half-grid dispatches (bbase = 0, 4096) so the top-5
   profile table surfaces the hidden hotspot kernels (visibility round). */
__global__ __launch_bounds__(256, 5) void k1_conv_gemm(
    const float* __restrict__ X,
    const float* __restrict__ wc1, const float* __restrict__ bc1,
    const float* __restrict__ wc2, const float* __restrict__ bc2,
    const float* __restrict__ wc3, const float* __restrict__ bc3,
    const float* __restrict__ acnn, float* __restrict__ ws, int bbase)
{
  __shared__ __align__(16) unsigned short t_s[32*TSTR];   /* 29,184 B */
  const int tid = threadIdx.x;
  const int b = bbase + blockIdx.x;
  const int wv = tid >> 6, lane = tid & 63;
  const int lrow = lane & 15, quad = lane >> 4;

  /* ---- Phase 0: async staging. X block = 4263 dwords -> 67 wave-chunks of 64 dw ---- */
  {
    const float* Xb = X + (size_t)b * (N_ * F_);
    unsigned* xd = (unsigned*)t_s;
    #pragma unroll
    for (int t = 0; t < 17; ++t) {
      int c = wv + 4*t;                      /* wave-uniform chunk id */
      if (c < 67) {
        int dw = c*64 + lane;
        int src = (dw < 4263) ? dw : 4262;   /* clamp tail lanes (garbage safe in LDS) */
        gload_lds4(Xb + src, xd + (size_t)c*64);
      }
    }
  }
  __syncthreads();

  const float c10 = wc1[0], c11 = wc1[1], c12 = wc1[2], b1 = bc1[0];
  const float c20 = wc2[0], c21 = wc2[1], c22 = wc2[2], c23 = wc2[3], c24 = wc2[4], b2 = bc2[0];
  const float c30 = wc3[0], c31 = wc3[1], c32 = wc3[2], c33 = wc3[3], c34 = wc3[4],
              c35 = wc3[5], c36 = wc3[6], b3 = bc3[0];
  const float ap = acnn[0];

  /* ---- Phase 1: extract 24-float window (segment f0 = 18*q, even) ---- */
  const int nC = tid >> 3, qC = tid & 7;
  const bool act = (nC < 29);
  const int f0 = qC * 18;
  const int nld = act ? nC : 28;
  float xv[24];
  {
    const float* xrow = (const float*)t_s + nld*147 + f0;
    #pragma unroll
    for (int i = 0; i < 24; ++i) xv[i] = xrow[i];
  }
  __syncthreads();

  /* ---- Phase 2: zero-fill pads + packed conv ---- */
  for (int i = tid; i < 3*448; i += 256) {
    int r = i / 448, c = i - r*448;
    t_s[(29 + r)*TSTR + c] = 0;
  }
  for (int i = tid; i < 29*19; i += 256) {
    int n = i / 19, j = i - n*19;
    int col = (j == 0) ? 145 : ((j == 1) ? 289 : (429 + j));
    t_s[n*TSTR + col] = 0;
  }

  {
    f32x2 s1v = (f32x2){0.f,0.f}, s2v = (f32x2){0.f,0.f};
    float s1t = 0.f, s2t = 0.f;
    unsigned short* tr = t_s + nC*TSTR + f0;
    if (act) {
      const int np2 = (qC < 7) ? 9 : 8;
      const int np3 = (qC < 7) ? 9 : 7;
      #pragma unroll
      for (int j = 0; j < 9; ++j) {
        const int k = 2*j;
        f32x2 xA = (f32x2){xv[k],   xv[k+1]};
        f32x2 xB = (f32x2){xv[k+1], xv[k+2]};
        f32x2 xC = (f32x2){xv[k+2], xv[k+3]};
        {
          f32x2 v1 = pfma(xA,c10, pfma(xB,c11, pfma(xC,c12, (f32x2){b1,b1})));
          v1 = prelu2(v1, ap);
          s1v += v1; s2v = __builtin_elementwise_fma(v1, v1, s2v);
          *(unsigned*)(tr + k) = packbf(v1);
        }
        if (j < np2) {
          f32x2 xD = (f32x2){xv[k+3], xv[k+4]};
          f32x2 xE = (f32x2){xv[k+4], xv[k+5]};
          f32x2 v2 = pfma(xA,c20, pfma(xB,c21, pfma(xC,c22, pfma(xD,c23, pfma(xE,c24, (f32x2){b2,b2})))));
          v2 = prelu2(v2, ap);
          s1v += v2; s2v = __builtin_elementwise_fma(v2, v2, s2v);
          *(unsigned*)(tr + 146 + k) = packbf(v2);
        }
        if (j < np3) {
          f32x2 xD = (f32x2){xv[k+3], xv[k+4]};
          f32x2 xE = (f32x2){xv[k+4], xv[k+5]};
          f32x2 xF = (f32x2){xv[k+5], xv[k+6]};
          f32x2 xG = (f32x2){xv[k+6], xv[k+7]};
          f32x2 v3 = pfma(xA,c30, pfma(xB,c31, pfma(xC,c32, pfma(xD,c33, pfma(xE,c34, pfma(xF,c35, pfma(xG,c36, (f32x2){b3,b3})))))));
          v3 = prelu2(v3, ap);
          s1v += v3; s2v = __builtin_elementwise_fma(v3, v3, s2v);
          *(unsigned*)(tr + 290 + k) = packbf(v3);
        }
      }
      if (qC == 7) {
        float u1 = fmaf(xv[18],c10, fmaf(xv[19],c11, fmaf(xv[20],c12, b1)));
        u1 = (u1 >= 0.f) ? u1 : ap*u1;
        s1t += u1; s2t = fmaf(u1, u1, s2t);
        tr[18] = f2bf(u1);
        float u2 = fmaf(xv[16],c20, fmaf(xv[17],c21, fmaf(xv[18],c22, fmaf(xv[19],c23, fmaf(xv[20],c24, b2)))));
        u2 = (u2 >= 0.f) ? u2 : ap*u2;
        s1t += u2; s2t = fmaf(u2, u2, s2t);
        tr[146 + 16] = f2bf(u2);
        float u3 = fmaf(xv[14],c30, fmaf(xv[15],c31, fmaf(xv[16],c32, fmaf(xv[17],c33, fmaf(xv[18],c34, fmaf(xv[19],c35, fmaf(xv[20],c36, b3)))))));
        u3 = (u3 >= 0.f) ? u3 : ap*u3;
        s1t += u3; s2t = fmaf(u3, u3, s2t);
        tr[290 + 14] = f2bf(u3);
      }
    }
    float s1 = s1v[0] + s1v[1] + s1t;
    float s2 = s2v[0] + s2v[1] + s2t;
    #pragma unroll
    for (int off = 4; off >= 1; off >>= 1) {
      s1 += __shfl_xor(s1, off);
      s2 += __shfl_xor(s2, off);
    }
    if (act && qC == 0) {
      float* bn1 = ws + BN1_OFF + (size_t)(b & 31) * 58;
      atomicAdd(&bn1[nC*2+0], s1);
      atomicAdd(&bn1[nC*2+1], s2);
    }
  }
  __syncthreads();

  /* ---- Phase 3: MFMA. wave wv covers output cols n0..n0+31, all 32 rows ---- */
  const int n0 = wv * 32;
  const unsigned short* imgp = (const unsigned short*)(ws + IMG_OFF);
  const unsigned short* gB0 = imgp + (size_t)(n0 + lrow)*448 + quad*8;
  const unsigned short* gB1 = gB0 + 16*448;
  const unsigned short* tA = t_s + quad*8;

  f32x4 a00 = (f32x4){0.f,0.f,0.f,0.f}, a01 = a00, a10 = a00, a11 = a00;
  bf16x8 Br0[2], Br1[2];
  Br0[0] = *(const bf16x8*)(gB0);
  Br1[0] = *(const bf16x8*)(gB1);
  Br0[1] = *(const bf16x8*)(gB0 + 32);
  Br1[1] = *(const bf16x8*)(gB1 + 32);
  #pragma unroll
  for (int ks = 0; ks < 14; ++ks) {
    bf16x8 Bc0 = Br0[ks & 1], Bc1 = Br1[ks & 1];
    if (ks < 12) {
      Br0[ks & 1] = *(const bf16x8*)(gB0 + (ks+2)*32);
      Br1[ks & 1] = *(const bf16x8*)(gB1 + (ks+2)*32);
    }
    bf16x8 A0 = *(const bf16x8*)(tA + lrow*TSTR + ks*32);
    bf16x8 A1 = *(const bf16x8*)(tA + (16+lrow)*TSTR + ks*32);
    a00 = __builtin_amdgcn_mfma_f32_16x16x32_bf16(A0, Bc0, a00, 0, 0, 0);
    a01 = __builtin_amdgcn_mfma_f32_16x16x32_bf16(A0, Bc1, a01, 0, 0, 0);
    a10 = __builtin_amdgcn_mfma_f32_16x16x32_bf16(A1, Bc0, a10, 0, 0, 0);
    a11 = __builtin_amdgcn_mfma_f32_16x16x32_bf16(A1, Bc1, a11, 0, 0, 0);
  }
  __syncthreads();

  {
    unsigned* ut32 = (unsigned*)t_s;
    const int fb0 = n0 + lrow, fb1 = n0 + 16 + lrow;
    #pragma unroll
    for (int jp = 0; jp < 2; ++jp) {
      int w = quad*2 + jp;
      ut32[fb0*17 + w]     = packbf((f32x2){a00[2*jp], a00[2*jp+1]});
      ut32[fb1*17 + w]     = packbf((f32x2){a01[2*jp], a01[2*jp+1]});
      ut32[fb0*17 + 8 + w] = packbf((f32x2){a10[2*jp], a10[2*jp+1]});
      ut32[fb1*17 + 8 + w] = packbf((f32x2){a11[2*jp], a11[2*jp+1]});
    }
  }
  __syncthreads();
  {
    const unsigned* u32t = (const unsigned*)t_s;
    unsigned short* ws16 = (unsigned short*)ws;
    unsigned* Ug = (unsigned*)(ws16 + (size_t)b * UTSTR);
    #pragma unroll
    for (int it = 0; it < 8; ++it) {
      int idx = tid + it*256;
      int f = idx >> 4, pr = idx & 15;
      Ug[f*16 + pr] = u32t[f*17 + pr];
    }
  }
}

/* K2: BN1 finalize ONCE. */
__global__ void k2_bn1f(float* __restrict__ ws)
{
  const int n = threadIdx.x;
  if (n < 29) {
    float s1 = 0.f, s2 = 0.f;
    #pragma unroll 4
    for (int s = 0; s < 32; ++s) {
      s1 += ws[BN1_OFF + s*58 + n*2 + 0];
      s2 += ws[BN1_OFF + s*58 + n*2 + 1];
    }
    const float inv = 1.f / (float)(B_ * DC);
    float mean = s1 * inv;
    float var  = s2 * inv - mean * mean;
    ws[FIN_OFF + n]      = mean;
    ws[FIN_OFF + 32 + n] = rsqrtf(var + EPSBN);
  }
}

/* K3: 2 batches per block with corr register-prefetch pipeline.
   y1 = prelu(corr@bn1(t)@Wg + bg); rowstats; bn2 stats. */
__global__ __launch_bounds__(256) void k3_gnn(
    const float* __restrict__ corr, const float* __restrict__ bg,
    const float* __restrict__ agnn, float* __restrict__ ws)
{
  __shared__ float cwf[841];
  __shared__ unsigned short a_s[32*40];
  __shared__ float m1s[29], is1s[29], cms[32];
  __shared__ float sts0[4][32], sts1[4][32], sts2[4][32];

  const int b0 = blockIdx.x * 2, tid = threadIdx.x;
  const int wv = tid >> 6, lane = tid & 63;
  const int lrow = lane & 15, quad = lane >> 4;
  const int f0 = wv * 32;

  if (tid < 29) {
    m1s[tid]  = ws[FIN_OFF + tid];
    is1s[tid] = ws[FIN_OFF + 32 + tid];
  }
  /* corr(b0) -> LDS, corr(b0+1) -> registers (latency hidden under batch 0) */
  const float* cb0 = corr + (size_t)b0 * 841;
  for (int i = tid; i < 841; i += 256) cwf[i] = cb0[i];
  float cnx[4];
  {
    const float* cb1 = cb0 + 841;
    #pragma unroll
    for (int k = 0; k < 4; ++k) {
      int idx = tid + k*256;
      cnx[k] = (idx < 841) ? cb1[idx] : 0.f;
    }
  }

  const float ag = agnn[0];
  const float vA  = ws[V_OFF  + f0 + lrow],      vB  = ws[V_OFF  + f0 + 16 + lrow];
  const float csA = ws[CSW_OFF + f0 + lrow],     csB = ws[CSW_OFF + f0 + 16 + lrow];
  const float bgA = bg[f0 + lrow],               bgB = bg[f0 + 16 + lrow];

  #pragma unroll
  for (int it = 0; it < 2; ++it) {
    const int b = b0 + it;
    unsigned short* Utb = (unsigned short*)ws + (size_t)b * UTSTR;

    /* issue B loads early; latency hides under barrier + a_s build */
    bf16x8 B0 = *(const bf16x8*)&Utb[(f0      + lrow)*32 + quad*8];
    bf16x8 B1 = *(const bf16x8*)&Utb[(f0 + 16 + lrow)*32 + quad*8];
    __syncthreads();   /* cwf for this batch visible; prev-iter LDS reads done */

    /* a_s = corr * is1 (bf16); cms[n] = sum_m corr[n,m]*is1[m]*m1[m] */
    {
      float pp[4];
      #pragma unroll
      for (int it2 = 0; it2 < 4; ++it2) {
        int i = tid + it2*256;
        int n = i >> 5, m = i & 31;
        bool val = (n < 29 && m < 29);
        float v = val ? cwf[n*29 + m] * is1s[m] : 0.f;
        a_s[n*40 + m] = f2bf(v);
        pp[it2] = val ? v * m1s[m] : 0.f;
      }
      #pragma unroll
      for (int off = 16; off >= 1; off >>= 1) {
        #pragma unroll
        for (int it2 = 0; it2 < 4; ++it2) pp[it2] += __shfl_xor(pp[it2], off);
      }
      #pragma unroll
      for (int it2 = 0; it2 < 4; ++it2) {
        int i = tid + it2*256;
        if ((i & 31) == 0 && (i >> 5) < 29) cms[i >> 5] = pp[it2];
      }
    }
    __syncthreads();   /* a_s + cms ready; cwf now dead */

    if (it == 0) {     /* overwrite cwf with next batch's corr from registers */
      #pragma unroll
      for (int k = 0; k < 4; ++k) {
        int idx = tid + k*256;
        if (idx < 841) cwf[idx] = cnx[k];
      }
    }

    bf16x8 A0 = *(const bf16x8*)&a_s[lrow*40 + quad*8];
    bf16x8 A1 = *(const bf16x8*)&a_s[(16 + lrow)*40 + quad*8];
    f32x4 acc[2][2];
    acc[0][0] = (f32x4){0.f,0.f,0.f,0.f}; acc[0][1] = (f32x4){0.f,0.f,0.f,0.f};
    acc[1][0] = (f32x4){0.f,0.f,0.f,0.f}; acc[1][1] = (f32x4){0.f,0.f,0.f,0.f};
    acc[0][0] = __builtin_amdgcn_mfma_f32_16x16x32_bf16(A0, B0, acc[0][0], 0, 0, 0);
    acc[0][1] = __builtin_amdgcn_mfma_f32_16x16x32_bf16(A0, B1, acc[0][1], 0, 0, 0);
    acc[1][0] = __builtin_amdgcn_mfma_f32_16x16x32_bf16(A1, B0, acc[1][0], 0, 0, 0);
    acc[1][1] = __builtin_amdgcn_mfma_f32_16x16x32_bf16(A1, B1, acc[1][1], 0, 0, 0);

    float psy[8], psy2[8], psv[8];
    #pragma unroll
    for (int mt = 0; mt < 2; ++mt) {
      #pragma unroll
      for (int i = 0; i < 4; ++i) {
        int idx = mt*4 + i;
        int n = mt*16 + quad*4 + i;
        float y0 = acc[mt][0][i] - cms[n & 31]*csA + bgA;
        float y1 = acc[mt][1][i] - cms[n & 31]*csB + bgB;
        y0 = (y0 >= 0.f) ? y0 : ag*y0;
        y1 = (y1 >= 0.f) ? y1 : ag*y1;
        if (n < 29) {
          Utb[n*D_ + f0 + lrow]      = f2bf(y0);
          Utb[n*D_ + f0 + 16 + lrow] = f2bf(y1);
        }
        psy[idx]  = y0 + y1;
        psy2[idx] = fmaf(y0, y0, y1*y1);
        psv[idx]  = fmaf(y0, vA, y1*vB);
      }
    }
    #pragma unroll
    for (int off = 8; off >= 1; off >>= 1) {
      #pragma unroll
      for (int idx = 0; idx < 8; ++idx) {
        psy[idx]  += __shfl_xor(psy[idx],  off);
        psy2[idx] += __shfl_xor(psy2[idx], off);
        psv[idx]  += __shfl_xor(psv[idx],  off);
      }
    }
    if (lrow == 0) {
      #pragma unroll
      for (int mt = 0; mt < 2; ++mt) {
        #pragma unroll
        for (int i = 0; i < 4; ++i) {
          int idx = mt*4 + i;
          int n = mt*16 + quad*4 + i;
          if (n < 29) {
            sts0[wv][n] = psy[idx];
            sts1[wv][n] = psy2[idx];
            sts2[wv][n] = psv[idx];
          }
        }
      }
    }
    __syncthreads();   /* sts ready; cwf-next writes done */
    if (tid < 29) {
      float S1 = sts0[0][tid] + sts0[1][tid] + sts0[2][tid] + sts0[3][tid];
      float S2 = sts1[0][tid] + sts1[1][tid] + sts1[2][tid] + sts1[3][tid];
      float Sv = sts2[0][tid] + sts2[1][tid] + sts2[2][tid] + sts2[3][tid];
      float* rs = (float*)(Utb + RS_SH);
      rs[tid]      = S1;
      rs[29 + tid] = S2;
      rs[58 + tid] = Sv;
      float* bn2 = ws + BN2_OFF + (size_t)(b & 31) * 58;
      atomicAdd(&bn2[tid*2+0], S1);
      atomicAdd(&bn2[tid*2+1], S2);
    }
  }
}

/* K4: 16 b per block (grid 512 -> 2 blocks/CU). bn2 finalize in-block;
   pooling (4 batches/wave) -> bf16 A-tile (M=16);
   x3 = A @ Wp^T (MFMA) - koff*cswp + bp; bn3 stats. */
__global__ __launch_bounds__(256) void k4_pool(
    const float* __restrict__ bpv, float* __restrict__ ws)
{
  __shared__ unsigned short Atile[KB4*ATSTR];   /* 4352 B */
  __shared__ float m2s[29], is2s[29], koffs[KB4];
  const int tid = threadIdx.x, wv = tid >> 6, lane = tid & 63;
  const int b0 = blockIdx.x * KB4;
  const unsigned short* U16 = (const unsigned short*)ws;

  if (tid < 29) {
    float s1 = 0.f, s2 = 0.f;
    #pragma unroll 4
    for (int s = 0; s < 32; ++s) {
      s1 += ws[BN2_OFF + s*58 + tid*2 + 0];
      s2 += ws[BN2_OFF + s*58 + tid*2 + 1];
    }
    const float inv = 1.f / (float)(B_ * D_);
    float mean = s1 * inv, var = s2 * inv - mean * mean;
    m2s[tid] = mean; is2s[tid] = rsqrtf(var + EPSBN);
  }
  __syncthreads();

  const float V1 = ws[V1_OFF];
  unsigned* At32 = (unsigned*)Atile;
  #pragma unroll
  for (int mb = 0; mb < 4; ++mb) {
    const int m = wv*4 + mb;
    const unsigned short* yb = U16 + (size_t)(b0 + m) * UTSTR;
    const float* rs = (const float*)(yb + RS_SH);
    float agg = -1e30f, m2 = 0.f, is2 = 0.f;
    if (lane < 29) {
      float S1 = rs[lane], S2 = rs[29+lane], Sv = rs[58+lane];
      m2 = m2s[lane]; is2 = is2s[lane];
      float ss = fmaxf(S2 - 2.f*m2*S1 + 128.f*m2*m2, 0.f);
      agg = (is2*(Sv - m2*V1)) / (is2*sqrtf(ss) + 1e-8f);
    }
    float mx = agg;
    #pragma unroll
    for (int off = 32; off >= 1; off >>= 1) mx = fmaxf(mx, __shfl_xor(mx, off));
    float e = (lane < 29) ? __expf(agg - mx) : 0.f;
    float den = e, kof = e*is2*m2;
    #pragma unroll
    for (int off = 32; off >= 1; off >>= 1) { den += __shfl_xor(den, off); kof += __shfl_xor(kof, off); }
    float rden = 1.f / den;
    float c = e * is2 * rden;
    if (lane == 0) koffs[m] = kof * rden;
    const unsigned* y32 = (const unsigned*)yb;
    float p0 = 0.f, p1 = 0.f;
    #pragma unroll
    for (int n = 0; n < 29; ++n) {
      float cn = __shfl(c, n);
      unsigned u = y32[n*64 + lane];
      p0 = fmaf(cn, bf2f(u & 0xffffu), p0);
      p1 = fmaf(cn, bf2f(u >> 16), p1);
    }
    At32[m*68 + lane] = (unsigned)f2bf(p0) | ((unsigned)f2bf(p1) << 16);
  }
  __syncthreads();

  const int lrow = lane & 15, quad = lane >> 4;
  const int n0 = wv * 32;
  const unsigned short* wpi = (const unsigned short*)(ws + WPI_OFF);
  f32x4 acc[2];
  acc[0] = (f32x4){0.f,0.f,0.f,0.f}; acc[1] = acc[0];
  #pragma unroll
  for (int ks = 0; ks < 4; ++ks) {
    bf16x8 A0 = *(const bf16x8*)&Atile[lrow*ATSTR + ks*32 + quad*8];
    bf16x8 Bq0 = *(const bf16x8*)&wpi[(size_t)(n0 + lrow)*128 + ks*32 + quad*8];
    bf16x8 Bq1 = *(const bf16x8*)&wpi[(size_t)(n0 + 16 + lrow)*128 + ks*32 + quad*8];
    acc[0] = __builtin_amdgcn_mfma_f32_16x16x32_bf16(A0, Bq0, acc[0], 0, 0, 0);
    acc[1] = __builtin_amdgcn_mfma_f32_16x16x32_bf16(A0, Bq1, acc[1], 0, 0, 0);
  }

  float* bn3 = ws + BN3_OFF + (size_t)(blockIdx.x & 31) * 256;
  #pragma unroll
  for (int nt = 0; nt < 2; ++nt) {
    int col = n0 + nt*16 + lrow;
    float cswp = ws[CSWP_OFF + col], bp = bpv[col];
    float s1c = 0.f, s2c = 0.f;
    #pragma unroll
    for (int i = 0; i < 4; ++i) {
      int m = quad*4 + i;
      float x3 = acc[nt][i] - koffs[m]*cswp + bp;
      ws[X3_OFF + (size_t)(b0 + m)*D_ + col] = x3;
      s1c += x3; s2c = fmaf(x3, x3, s2c);
    }
    s1c += __shfl_xor(s1c, 16); s1c += __shfl_xor(s1c, 32);
    s2c += __shfl_xor(s2c, 16); s2c += __shfl_xor(s2c, 32);
    if (quad == 0) {
      atomicAdd(&bn3[col*2+0], s1c);
      atomicAdd(&bn3[col*2+1], s2c);
    }
  }
}

/* K5: 16 b per block (grid 512). bn3 finalize in-block;
   h = prelu(bn3(x3)@Wm1 + bm1) (MFMA, M=16); logit -> sigmoid. */
__global__ __launch_bounds__(256) void k5_mlp(
    const float* __restrict__ bm1, const float* __restrict__ amlp,
    const float* __restrict__ Wm2, const float* __restrict__ bm2,
    float* __restrict__ ws, float* __restrict__ out)
{
  __shared__ unsigned short Atile[KB4*ATSTR];
  __shared__ float m3s[128], is3s[128], logit_s[KB4];
  const int tid = threadIdx.x, wv = tid >> 6, lane = tid & 63;
  const int b0 = blockIdx.x * KB4;

  if (tid < 128) {
    float s1 = 0.f, s2 = 0.f;
    #pragma unroll 4
    for (int s = 0; s < 32; ++s) {
      s1 += ws[BN3_OFF + s*256 + tid*2 + 0];
      s2 += ws[BN3_OFF + s*256 + tid*2 + 1];
    }
    const float inv = 1.f / (float)B_;
    float mean = s1 * inv, var = s2 * inv - mean * mean;
    m3s[tid] = mean; is3s[tid] = rsqrtf(var + EPSBN);
  }
  if (tid >= 128 && tid < 128 + KB4) logit_s[tid-128] = 0.f;
  __syncthreads();

  #pragma unroll
  for (int it = 0; it < 8; ++it) {
    int idx = tid + it*256;
    int row = idx >> 7, col = idx & 127;
    float v = (ws[X3_OFF + (size_t)(b0+row)*D_ + col] - m3s[col]) * is3s[col];
    Atile[row*ATSTR + col] = f2bf(v);
  }
  __syncthreads();

  const int lrow = lane & 15, quad = lane >> 4;
  const int n0 = wv * 32;
  const unsigned short* wmi = (const unsigned short*)(ws + WM1I_OFF);
  f32x4 acc[2];
  acc[0] = (f32x4){0.f,0.f,0.f,0.f}; acc[1] = acc[0];
  #pragma unroll
  for (int ks = 0; ks < 4; ++ks) {
    bf16x8 A0 = *(const bf16x8*)&Atile[lrow*ATSTR + ks*32 + quad*8];
    bf16x8 Bq0 = *(const bf16x8*)&wmi[(size_t)(n0 + lrow)*128 + ks*32 + quad*8];
    bf16x8 Bq1 = *(const bf16x8*)&wmi[(size_t)(n0 + 16 + lrow)*128 + ks*32 + quad*8];
    acc[0] = __builtin_amdgcn_mfma_f32_16x16x32_bf16(A0, Bq0, acc[0], 0, 0, 0);
    acc[1] = __builtin_amdgcn_mfma_f32_16x16x32_bf16(A0, Bq1, acc[1], 0, 0, 0);
  }

  const float am = amlp[0];
  float bmc[2], wm2c[2];
  #pragma unroll
  for (int nt = 0; nt < 2; ++nt) {
    int col = n0 + nt*16 + lrow;
    bmc[nt] = bm1[col]; wm2c[nt] = Wm2[col];
  }
  #pragma unroll
  for (int i = 0; i < 4; ++i) {
    float pm = 0.f;
    #pragma unroll
    for (int nt = 0; nt < 2; ++nt) {
      float h = acc[nt][i] + bmc[nt];
      h = (h >= 0.f) ? h : am*h;
      pm = fmaf(h, wm2c[nt], pm);
    }
    #pragma unroll
    for (int off = 8; off >= 1; off >>= 1) pm += __shfl_xor(pm, off);
    if (lrow == 0) atomicAdd(&logit_s[quad*4 + i], pm);
  }
  __syncthreads();
  if (tid < KB4) {
    float logit = logit_s[tid] + bm2[0];
    out[b0 + tid] = 1.f / (1.f + expf(-logit));
  }
}

extern "C" void kernel_launch(void* const* d_in, const int* in_sizes, int n_in,
                              void* d_out, int out_size, void* d_ws, size_t ws_size,
                              hipStream_t stream)
{
  (void)in_sizes; (void)n_in; (void)out_size; (void)ws_size;
  const float* X    = (const float*)d_in[0];
  const float* corr = (const float*)d_in[1];
  const float* wc1  = (const float*)d_in[2];
  const float* bc1  = (const float*)d_in[3];
  const float* wc2  = (const float*)d_in[4];
  const float* bc2  = (const float*)d_in[5];
  const float* wc3  = (const float*)d_in[6];
  const float* bc3  = (const float*)d_in[7];
  const float* acnn = (const float*)d_in[8];
  const float* Wg   = (const float*)d_in[9];
  const float* bg   = (const float*)d_in[10];
  const float* agnn = (const float*)d_in[11];
  const float* cent = (const float*)d_in[12];
  const float* hw   = (const float*)d_in[13];
  const float* Wp   = (const float*)d_in[14];
  const float* bp   = (const float*)d_in[15];
  const float* Wm1  = (const float*)d_in[16];
  const float* bm1  = (const float*)d_in[17];
  const float* amlp = (const float*)d_in[18];
  const float* Wm2  = (const float*)d_in[19];
  const float* bm2  = (const float*)d_in[20];
  float* ws  = (float*)d_ws;
  float* out = (float*)d_out;

  k0_setup<<<19, 256, 0, stream>>>(Wg, Wp, Wm1, cent, hw, ws);
  /* k1 split into two half-grid dispatches: each ~75 µs so the top-5
     profile table surfaces the hidden k3/k4/k5 hotspot with counters. */
  k1_conv_gemm<<<B_/2, 256, 0, stream>>>(X, wc1, bc1, wc2, bc2, wc3, bc3, acnn, ws, 0);
  k1_conv_gemm<<<B_/2, 256, 0, stream>>>(X, wc1, bc1, wc2, bc2, wc3, bc3, acnn, ws, B_/2);
  k2_bn1f<<<1, 64, 0, stream>>>(ws);
  k3_gnn<<<B_/2, 256, 0, stream>>>(corr, bg, agnn, ws);
  k4_pool<<<B_/KB4, 256, 0, stream>>>(bp, ws);
  k5_mlp<<<B_/KB4, 256, 0, stream>>>(bm1, amlp, Wm2, bm2, ws, out);
}

// Round 9
// 446.132 us; speedup vs baseline: 1.0368x; 1.0368x over previous
//
#include <hip/hip_runtime.h>

#define B_    8192
#define N_    29
#define F_    147
#define DC    429
#define D_    128
#define ROWS  (B_*N_)
#define EPSBN 1e-5f

#define UTSTR   4096                        /* shorts per b */
#define RS_SH   3712                        /* short offset of rowstats */

/* ws layout in float units */
#define X3_OFF   16777216                   /* fp32 B_*128 */
#define ACC_OFF  (X3_OFF + B_*D_)
#define BN1_OFF  (ACC_OFF)                  /* 32*29*2 */
#define BN2_OFF  (ACC_OFF + 1856)
#define BN3_OFF  (ACC_OFF + 3712)           /* 32*128*2 */
#define FIN_OFF  (ACC_OFF + 11904)
/* FIN_OFF+0..28: m1s (k2 out), FIN_OFF+32..60: is1s (k2 out) */
#define CSW_OFF  (FIN_OFF + 384)
#define V_OFF    (FIN_OFF + 512)
#define V1_OFF   (FIN_OFF + 640)
#define CSWP_OFF (FIN_OFF + 768)
#define IMG_OFF  (FIN_OFF + 1024)           /* bf16 Wg image: 128*448 shorts */
#define WPI_OFF  (IMG_OFF + 28672)          /* bf16 Wp^T image: 128*128 shorts */
#define WM1I_OFF (WPI_OFF + 8192)           /* bf16 Wm1^T image */

typedef __bf16 bf16x8 __attribute__((ext_vector_type(8)));
typedef float  f32x4  __attribute__((ext_vector_type(4)));
typedef float  f32x2  __attribute__((ext_vector_type(2)));

__device__ __forceinline__ unsigned short f2bf(float f) {
  __bf16 h = (__bf16)f;
  return __builtin_bit_cast(unsigned short, h);
}
__device__ __forceinline__ float bf2f(unsigned u16) {
  return __uint_as_float(u16 << 16);
}
__device__ __forceinline__ unsigned packbf(f32x2 v) {
  return (unsigned)f2bf(v[0]) | ((unsigned)f2bf(v[1]) << 16);
}
__device__ __forceinline__ f32x2 pfma(f32x2 a, float s, f32x2 c) {
  return __builtin_elementwise_fma(a, (f32x2){s, s}, c);
}
__device__ __forceinline__ f32x2 prelu2(f32x2 v, float a) {
  f32x2 z = (f32x2){0.f, 0.f};
  return __builtin_elementwise_fma(__builtin_elementwise_min(v, z), (f32x2){a, a},
                                   __builtin_elementwise_max(v, z));
}
__device__ __forceinline__ void gload_lds4(const float* g, void* l) {
  __builtin_amdgcn_global_load_lds((const __attribute__((address_space(1))) void*)g,
                                   (__attribute__((address_space(3))) void*)l, 4, 0, 0);
}

#define TSTR 456
#define UTILS 34
#define ATSTR 136  /* k4/k5 A-tile stride (shorts) */
#define KB4 16     /* batches per k4/k5 block */

/* K0: Wg image + colsum (blocks 0..15); Wp^T image + colsum (16); Wm1^T image (17);
   centroid vector + V1 + ACC zero (18). */
__global__ void k0_setup(const float* __restrict__ Wg, const float* __restrict__ Wp,
                         const float* __restrict__ Wm1, const float* __restrict__ cent,
                         const float* __restrict__ hw, float* __restrict__ ws)
{
  const int tid = threadIdx.x;
  if (blockIdx.x < 16) {
    __shared__ float cs_l[8];
    const int kb = blockIdx.x * 8;
    if (tid < 8) cs_l[tid] = 0.f;
    __syncthreads();
    unsigned short* img = (unsigned short*)(ws + IMG_OFF);
    for (int i = tid; i < 8*448; i += 256) {
      int kk = i / 448, dk = i - kk*448;
      int k = kb + kk;
      int d;
      if      (dk < 145)  d = dk;
      else if (dk == 145) d = -1;
      else if (dk < 289)  d = dk - 1;
      else if (dk == 289) d = -1;
      else if (dk < 431)  d = dk - 2;
      else                d = -1;
      float v = (d >= 0) ? Wg[(size_t)d*D_ + k] : 0.f;
      img[(size_t)k*448 + dk] = f2bf(v);
      if (d >= 0) atomicAdd(&cs_l[kk], v);
    }
    __syncthreads();
    if (tid < 8) ws[CSW_OFF + kb + tid] = cs_l[tid];
  } else if (blockIdx.x == 16) {
    unsigned short* wpi = (unsigned short*)(ws + WPI_OFF);
    for (int i = tid; i < 16384; i += 256) {
      int k = i >> 7, c = i & 127;
      wpi[c*128 + k] = f2bf(Wp[k*128 + c]);
    }
    if (tid < 128) {
      float s = 0.f;
      for (int k = 0; k < 128; ++k) s += Wp[k*128 + tid];
      ws[CSWP_OFF + tid] = s;
    }
  } else if (blockIdx.x == 17) {
    unsigned short* wmi = (unsigned short*)(ws + WM1I_OFF);
    for (int i = tid; i < 16384; i += 256) {
      int k = i >> 7, c = i & 127;
      wmi[c*128 + k] = f2bf(Wm1[k*128 + c]);
    }
  } else {
    const int wv = tid >> 6, lane = tid & 63;
    if (wv == 0) {
      float vk0 = 0.f, vk1 = 0.f;
      for (int h = 0; h < 4; ++h) {
        float c0 = cent[h*D_ + lane];
        float c1 = cent[h*D_ + 64 + lane];
        float s = c0*c0 + c1*c1;
        #pragma unroll
        for (int off = 32; off >= 1; off >>= 1) s += __shfl_xor(s, off);
        float w = hw[h] / (sqrtf(s) + 1e-8f);
        vk0 = fmaf(c0, w, vk0);
        vk1 = fmaf(c1, w, vk1);
      }
      ws[V_OFF + lane]      = vk0;
      ws[V_OFF + 64 + lane] = vk1;
      float t = vk0 + vk1;
      #pragma unroll
      for (int off = 32; off >= 1; off >>= 1) t += __shfl_xor(t, off);
      if (lane == 0) ws[V1_OFF] = t;
    } else {
      for (int i = tid - 64; i < 11904; i += 192) ws[ACC_OFF + i] = 0.f;
    }
  }
}

/* K1: 1 b per block, 256 threads, LDS 29,184 B -> 5 blocks/CU.
   r6 config + (a) 4-deep B preload hoisted BEFORE the pre-MFMA barrier
   (L2 latency hides under barrier wait), (b) distance-4 B ring,
   (c) s_setprio(1) around the MFMA loop (phase-diverse blocks on CU). */
__global__ __launch_bounds__(256, 5) void k1_conv_gemm(
    const float* __restrict__ X,
    const float* __restrict__ wc1, const float* __restrict__ bc1,
    const float* __restrict__ wc2, const float* __restrict__ bc2,
    const float* __restrict__ wc3, const float* __restrict__ bc3,
    const float* __restrict__ acnn, float* __restrict__ ws)
{
  __shared__ __align__(16) unsigned short t_s[32*TSTR];   /* 29,184 B */
  const int tid = threadIdx.x;
  const int b = blockIdx.x;
  const int wv = tid >> 6, lane = tid & 63;
  const int lrow = lane & 15, quad = lane >> 4;

  /* ---- Phase 0: async staging. X block = 4263 dwords -> 67 wave-chunks of 64 dw ---- */
  {
    const float* Xb = X + (size_t)b * (N_ * F_);
    unsigned* xd = (unsigned*)t_s;
    #pragma unroll
    for (int t = 0; t < 17; ++t) {
      int c = wv + 4*t;                      /* wave-uniform chunk id */
      if (c < 67) {
        int dw = c*64 + lane;
        int src = (dw < 4263) ? dw : 4262;   /* clamp tail lanes (garbage safe in LDS) */
        gload_lds4(Xb + src, xd + (size_t)c*64);
      }
    }
  }
  __syncthreads();

  const float c10 = wc1[0], c11 = wc1[1], c12 = wc1[2], b1 = bc1[0];
  const float c20 = wc2[0], c21 = wc2[1], c22 = wc2[2], c23 = wc2[3], c24 = wc2[4], b2 = bc2[0];
  const float c30 = wc3[0], c31 = wc3[1], c32 = wc3[2], c33 = wc3[3], c34 = wc3[4],
              c35 = wc3[5], c36 = wc3[6], b3 = bc3[0];
  const float ap = acnn[0];

  /* ---- Phase 1: extract 24-float window (segment f0 = 18*q, even) ---- */
  const int nC = tid >> 3, qC = tid & 7;
  const bool act = (nC < 29);
  const int f0 = qC * 18;
  const int nld = act ? nC : 28;
  float xv[24];
  {
    const float* xrow = (const float*)t_s + nld*147 + f0;
    #pragma unroll
    for (int i = 0; i < 24; ++i) xv[i] = xrow[i];
  }
  __syncthreads();

  /* ---- Phase 2: zero-fill pads + packed conv ---- */
  for (int i = tid; i < 3*448; i += 256) {
    int r = i / 448, c = i - r*448;
    t_s[(29 + r)*TSTR + c] = 0;
  }
  for (int i = tid; i < 29*19; i += 256) {
    int n = i / 19, j = i - n*19;
    int col = (j == 0) ? 145 : ((j == 1) ? 289 : (429 + j));
    t_s[n*TSTR + col] = 0;
  }

  {
    f32x2 s1v = (f32x2){0.f,0.f}, s2v = (f32x2){0.f,0.f};
    float s1t = 0.f, s2t = 0.f;
    unsigned short* tr = t_s + nC*TSTR + f0;
    if (act) {
      const int np2 = (qC < 7) ? 9 : 8;
      const int np3 = (qC < 7) ? 9 : 7;
      #pragma unroll
      for (int j = 0; j < 9; ++j) {
        const int k = 2*j;
        f32x2 xA = (f32x2){xv[k],   xv[k+1]};
        f32x2 xB = (f32x2){xv[k+1], xv[k+2]};
        f32x2 xC = (f32x2){xv[k+2], xv[k+3]};
        {
          f32x2 v1 = pfma(xA,c10, pfma(xB,c11, pfma(xC,c12, (f32x2){b1,b1})));
          v1 = prelu2(v1, ap);
          s1v += v1; s2v = __builtin_elementwise_fma(v1, v1, s2v);
          *(unsigned*)(tr + k) = packbf(v1);
        }
        if (j < np2) {
          f32x2 xD = (f32x2){xv[k+3], xv[k+4]};
          f32x2 xE = (f32x2){xv[k+4], xv[k+5]};
          f32x2 v2 = pfma(xA,c20, pfma(xB,c21, pfma(xC,c22, pfma(xD,c23, pfma(xE,c24, (f32x2){b2,b2})))));
          v2 = prelu2(v2, ap);
          s1v += v2; s2v = __builtin_elementwise_fma(v2, v2, s2v);
          *(unsigned*)(tr + 146 + k) = packbf(v2);
        }
        if (j < np3) {
          f32x2 xD = (f32x2){xv[k+3], xv[k+4]};
          f32x2 xE = (f32x2){xv[k+4], xv[k+5]};
          f32x2 xF = (f32x2){xv[k+5], xv[k+6]};
          f32x2 xG = (f32x2){xv[k+6], xv[k+7]};
          f32x2 v3 = pfma(xA,c30, pfma(xB,c31, pfma(xC,c32, pfma(xD,c33, pfma(xE,c34, pfma(xF,c35, pfma(xG,c36, (f32x2){b3,b3})))))));
          v3 = prelu2(v3, ap);
          s1v += v3; s2v = __builtin_elementwise_fma(v3, v3, s2v);
          *(unsigned*)(tr + 290 + k) = packbf(v3);
        }
      }
      if (qC == 7) {
        float u1 = fmaf(xv[18],c10, fmaf(xv[19],c11, fmaf(xv[20],c12, b1)));
        u1 = (u1 >= 0.f) ? u1 : ap*u1;
        s1t += u1; s2t = fmaf(u1, u1, s2t);
        tr[18] = f2bf(u1);
        float u2 = fmaf(xv[16],c20, fmaf(xv[17],c21, fmaf(xv[18],c22, fmaf(xv[19],c23, fmaf(xv[20],c24, b2)))));
        u2 = (u2 >= 0.f) ? u2 : ap*u2;
        s1t += u2; s2t = fmaf(u2, u2, s2t);
        tr[146 + 16] = f2bf(u2);
        float u3 = fmaf(xv[14],c30, fmaf(xv[15],c31, fmaf(xv[16],c32, fmaf(xv[17],c33, fmaf(xv[18],c34, fmaf(xv[19],c35, fmaf(xv[20],c36, b3)))))));
        u3 = (u3 >= 0.f) ? u3 : ap*u3;
        s1t += u3; s2t = fmaf(u3, u3, s2t);
        tr[290 + 14] = f2bf(u3);
      }
    }
    float s1 = s1v[0] + s1v[1] + s1t;
    float s2 = s2v[0] + s2v[1] + s2t;
    #pragma unroll
    for (int off = 4; off >= 1; off >>= 1) {
      s1 += __shfl_xor(s1, off);
      s2 += __shfl_xor(s2, off);
    }
    if (act && qC == 0) {
      float* bn1 = ws + BN1_OFF + (size_t)(b & 31) * 58;
      atomicAdd(&bn1[nC*2+0], s1);
      atomicAdd(&bn1[nC*2+1], s2);
    }
  }

  /* ---- Phase 3 setup: B pointers + 4-deep preload BEFORE the barrier ---- */
  const int n0 = wv * 32;
  const unsigned short* imgp = (const unsigned short*)(ws + IMG_OFF);
  const unsigned short* gB0 = imgp + (size_t)(n0 + lrow)*448 + quad*8;
  const unsigned short* gB1 = gB0 + 16*448;
  bf16x8 Br0[4], Br1[4];
  #pragma unroll
  for (int j = 0; j < 4; ++j) {
    Br0[j] = *(const bf16x8*)(gB0 + j*32);
    Br1[j] = *(const bf16x8*)(gB1 + j*32);
  }
  __syncthreads();

  /* ---- Phase 3: MFMA. wave wv covers output cols n0..n0+31, all 32 rows ---- */
  const unsigned short* tA = t_s + quad*8;
  f32x4 a00 = (f32x4){0.f,0.f,0.f,0.f}, a01 = a00, a10 = a00, a11 = a00;
  __builtin_amdgcn_s_setprio(1);
  #pragma unroll
  for (int ks = 0; ks < 14; ++ks) {
    bf16x8 Bc0 = Br0[ks & 3], Bc1 = Br1[ks & 3];
    if (ks < 10) {
      Br0[ks & 3] = *(const bf16x8*)(gB0 + (ks+4)*32);
      Br1[ks & 3] = *(const bf16x8*)(gB1 + (ks+4)*32);
    }
    bf16x8 A0 = *(const bf16x8*)(tA + lrow*TSTR + ks*32);
    bf16x8 A1 = *(const bf16x8*)(tA + (16+lrow)*TSTR + ks*32);
    a00 = __builtin_amdgcn_mfma_f32_16x16x32_bf16(A0, Bc0, a00, 0, 0, 0);
    a01 = __builtin_amdgcn_mfma_f32_16x16x32_bf16(A0, Bc1, a01, 0, 0, 0);
    a10 = __builtin_amdgcn_mfma_f32_16x16x32_bf16(A1, Bc0, a10, 0, 0, 0);
    a11 = __builtin_amdgcn_mfma_f32_16x16x32_bf16(A1, Bc1, a11, 0, 0, 0);
  }
  __builtin_amdgcn_s_setprio(0);
  __syncthreads();

  {
    unsigned* ut32 = (unsigned*)t_s;
    const int fb0 = n0 + lrow, fb1 = n0 + 16 + lrow;
    #pragma unroll
    for (int jp = 0; jp < 2; ++jp) {
      int w = quad*2 + jp;
      ut32[fb0*17 + w]     = packbf((f32x2){a00[2*jp], a00[2*jp+1]});
      ut32[fb1*17 + w]     = packbf((f32x2){a01[2*jp], a01[2*jp+1]});
      ut32[fb0*17 + 8 + w] = packbf((f32x2){a10[2*jp], a10[2*jp+1]});
      ut32[fb1*17 + 8 + w] = packbf((f32x2){a11[2*jp], a11[2*jp+1]});
    }
  }
  __syncthreads();
  {
    const unsigned* u32t = (const unsigned*)t_s;
    unsigned short* ws16 = (unsigned short*)ws;
    unsigned* Ug = (unsigned*)(ws16 + (size_t)b * UTSTR);
    #pragma unroll
    for (int it = 0; it < 8; ++it) {
      int idx = tid + it*256;
      int f = idx >> 4, pr = idx & 15;
      Ug[f*16 + pr] = u32t[f*17 + pr];
    }
  }
}

/* K2: BN1 finalize ONCE. */
__global__ void k2_bn1f(float* __restrict__ ws)
{
  const int n = threadIdx.x;
  if (n < 29) {
    float s1 = 0.f, s2 = 0.f;
    #pragma unroll 4
    for (int s = 0; s < 32; ++s) {
      s1 += ws[BN1_OFF + s*58 + n*2 + 0];
      s2 += ws[BN1_OFF + s*58 + n*2 + 1];
    }
    const float inv = 1.f / (float)(B_ * DC);
    float mean = s1 * inv;
    float var  = s2 * inv - mean * mean;
    ws[FIN_OFF + n]      = mean;
    ws[FIN_OFF + 32 + n] = rsqrtf(var + EPSBN);
  }
}

/* K3: 2 batches per block with corr register-prefetch pipeline.
   y1 = prelu(corr@bn1(t)@Wg + bg); rowstats; bn2 stats. */
__global__ __launch_bounds__(256) void k3_gnn(
    const float* __restrict__ corr, const float* __restrict__ bg,
    const float* __restrict__ agnn, float* __restrict__ ws)
{
  __shared__ float cwf[841];
  __shared__ unsigned short a_s[32*40];
  __shared__ float m1s[29], is1s[29], cms[32];
  __shared__ float sts0[4][32], sts1[4][32], sts2[4][32];

  const int b0 = blockIdx.x * 2, tid = threadIdx.x;
  const int wv = tid >> 6, lane = tid & 63;
  const int lrow = lane & 15, quad = lane >> 4;
  const int f0 = wv * 32;

  if (tid < 29) {
    m1s[tid]  = ws[FIN_OFF + tid];
    is1s[tid] = ws[FIN_OFF + 32 + tid];
  }
  /* corr(b0) -> LDS, corr(b0+1) -> registers (latency hidden under batch 0) */
  const float* cb0 = corr + (size_t)b0 * 841;
  for (int i = tid; i < 841; i += 256) cwf[i] = cb0[i];
  float cnx[4];
  {
    const float* cb1 = cb0 + 841;
    #pragma unroll
    for (int k = 0; k < 4; ++k) {
      int idx = tid + k*256;
      cnx[k] = (idx < 841) ? cb1[idx] : 0.f;
    }
  }

  const float ag = agnn[0];
  const float vA  = ws[V_OFF  + f0 + lrow],      vB  = ws[V_OFF  + f0 + 16 + lrow];
  const float csA = ws[CSW_OFF + f0 + lrow],     csB = ws[CSW_OFF + f0 + 16 + lrow];
  const float bgA = bg[f0 + lrow],               bgB = bg[f0 + 16 + lrow];

  #pragma unroll
  for (int it = 0; it < 2; ++it) {
    const int b = b0 + it;
    unsigned short* Utb = (unsigned short*)ws + (size_t)b * UTSTR;

    /* issue B loads early; latency hides under barrier + a_s build */
    bf16x8 B0 = *(const bf16x8*)&Utb[(f0      + lrow)*32 + quad*8];
    bf16x8 B1 = *(const bf16x8*)&Utb[(f0 + 16 + lrow)*32 + quad*8];
    __syncthreads();   /* cwf for this batch visible; prev-iter LDS reads done */

    /* a_s = corr * is1 (bf16); cms[n] = sum_m corr[n,m]*is1[m]*m1[m] */
    {
      float pp[4];
      #pragma unroll
      for (int it2 = 0; it2 < 4; ++it2) {
        int i = tid + it2*256;
        int n = i >> 5, m = i & 31;
        bool val = (n < 29 && m < 29);
        float v = val ? cwf[n*29 + m] * is1s[m] : 0.f;
        a_s[n*40 + m] = f2bf(v);
        pp[it2] = val ? v * m1s[m] : 0.f;
      }
      #pragma unroll
      for (int off = 16; off >= 1; off >>= 1) {
        #pragma unroll
        for (int it2 = 0; it2 < 4; ++it2) pp[it2] += __shfl_xor(pp[it2], off);
      }
      #pragma unroll
      for (int it2 = 0; it2 < 4; ++it2) {
        int i = tid + it2*256;
        if ((i & 31) == 0 && (i >> 5) < 29) cms[i >> 5] = pp[it2];
      }
    }
    __syncthreads();   /* a_s + cms ready; cwf now dead */

    if (it == 0) {     /* overwrite cwf with next batch's corr from registers */
      #pragma unroll
      for (int k = 0; k < 4; ++k) {
        int idx = tid + k*256;
        if (idx < 841) cwf[idx] = cnx[k];
      }
    }

    bf16x8 A0 = *(const bf16x8*)&a_s[lrow*40 + quad*8];
    bf16x8 A1 = *(const bf16x8*)&a_s[(16 + lrow)*40 + quad*8];
    f32x4 acc[2][2];
    acc[0][0] = (f32x4){0.f,0.f,0.f,0.f}; acc[0][1] = (f32x4){0.f,0.f,0.f,0.f};
    acc[1][0] = (f32x4){0.f,0.f,0.f,0.f}; acc[1][1] = (f32x4){0.f,0.f,0.f,0.f};
    acc[0][0] = __builtin_amdgcn_mfma_f32_16x16x32_bf16(A0, B0, acc[0][0], 0, 0, 0);
    acc[0][1] = __builtin_amdgcn_mfma_f32_16x16x32_bf16(A0, B1, acc[0][1], 0, 0, 0);
    acc[1][0] = __builtin_amdgcn_mfma_f32_16x16x32_bf16(A1, B0, acc[1][0], 0, 0, 0);
    acc[1][1] = __builtin_amdgcn_mfma_f32_16x16x32_bf16(A1, B1, acc[1][1], 0, 0, 0);

    float psy[8], psy2[8], psv[8];
    #pragma unroll
    for (int mt = 0; mt < 2; ++mt) {
      #pragma unroll
      for (int i = 0; i < 4; ++i) {
        int idx = mt*4 + i;
        int n = mt*16 + quad*4 + i;
        float y0 = acc[mt][0][i] - cms[n & 31]*csA + bgA;
        float y1 = acc[mt][1][i] - cms[n & 31]*csB + bgB;
        y0 = (y0 >= 0.f) ? y0 : ag*y0;
        y1 = (y1 >= 0.f) ? y1 : ag*y1;
        if (n < 29) {
          Utb[n*D_ + f0 + lrow]      = f2bf(y0);
          Utb[n*D_ + f0 + 16 + lrow] = f2bf(y1);
        }
        psy[idx]  = y0 + y1;
        psy2[idx] = fmaf(y0, y0, y1*y1);
        psv[idx]  = fmaf(y0, vA, y1*vB);
      }
    }
    #pragma unroll
    for (int off = 8; off >= 1; off >>= 1) {
      #pragma unroll
      for (int idx = 0; idx < 8; ++idx) {
        psy[idx]  += __shfl_xor(psy[idx],  off);
        psy2[idx] += __shfl_xor(psy2[idx], off);
        psv[idx]  += __shfl_xor(psv[idx],  off);
      }
    }
    if (lrow == 0) {
      #pragma unroll
      for (int mt = 0; mt < 2; ++mt) {
        #pragma unroll
        for (int i = 0; i < 4; ++i) {
          int idx = mt*4 + i;
          int n = mt*16 + quad*4 + i;
          if (n < 29) {
            sts0[wv][n] = psy[idx];
            sts1[wv][n] = psy2[idx];
            sts2[wv][n] = psv[idx];
          }
        }
      }
    }
    __syncthreads();   /* sts ready; cwf-next writes done */
    if (tid < 29) {
      float S1 = sts0[0][tid] + sts0[1][tid] + sts0[2][tid] + sts0[3][tid];
      float S2 = sts1[0][tid] + sts1[1][tid] + sts1[2][tid] + sts1[3][tid];
      float Sv = sts2[0][tid] + sts2[1][tid] + sts2[2][tid] + sts2[3][tid];
      float* rs = (float*)(Utb + RS_SH);
      rs[tid]      = S1;
      rs[29 + tid] = S2;
      rs[58 + tid] = Sv;
      float* bn2 = ws + BN2_OFF + (size_t)(b & 31) * 58;
      atomicAdd(&bn2[tid*2+0], S1);
      atomicAdd(&bn2[tid*2+1], S2);
    }
  }
}

/* K4: 16 b per block (grid 512 -> 2 blocks/CU). bn2 finalize in-block;
   pooling (4 batches/wave) -> bf16 A-tile (M=16);
   x3 = A @ Wp^T (MFMA) - koff*cswp + bp; bn3 stats. */
__global__ __launch_bounds__(256) void k4_pool(
    const float* __restrict__ bpv, float* __restrict__ ws)
{
  __shared__ unsigned short Atile[KB4*ATSTR];   /* 4352 B */
  __shared__ float m2s[29], is2s[29], koffs[KB4];
  const int tid = threadIdx.x, wv = tid >> 6, lane = tid & 63;
  const int b0 = blockIdx.x * KB4;
  const unsigned short* U16 = (const unsigned short*)ws;

  if (tid < 29) {
    float s1 = 0.f, s2 = 0.f;
    #pragma unroll 4
    for (int s = 0; s < 32; ++s) {
      s1 += ws[BN2_OFF + s*58 + tid*2 + 0];
      s2 += ws[BN2_OFF + s*58 + tid*2 + 1];
    }
    const float inv = 1.f / (float)(B_ * D_);
    float mean = s1 * inv, var = s2 * inv - mean * mean;
    m2s[tid] = mean; is2s[tid] = rsqrtf(var + EPSBN);
  }
  __syncthreads();

  const float V1 = ws[V1_OFF];
  unsigned* At32 = (unsigned*)Atile;
  #pragma unroll
  for (int mb = 0; mb < 4; ++mb) {
    const int m = wv*4 + mb;
    const unsigned short* yb = U16 + (size_t)(b0 + m) * UTSTR;
    const float* rs = (const float*)(yb + RS_SH);
    float agg = -1e30f, m2 = 0.f, is2 = 0.f;
    if (lane < 29) {
      float S1 = rs[lane], S2 = rs[29+lane], Sv = rs[58+lane];
      m2 = m2s[lane]; is2 = is2s[lane];
      float ss = fmaxf(S2 - 2.f*m2*S1 + 128.f*m2*m2, 0.f);
      agg = (is2*(Sv - m2*V1)) / (is2*sqrtf(ss) + 1e-8f);
    }
    float mx = agg;
    #pragma unroll
    for (int off = 32; off >= 1; off >>= 1) mx = fmaxf(mx, __shfl_xor(mx, off));
    float e = (lane < 29) ? __expf(agg - mx) : 0.f;
    float den = e, kof = e*is2*m2;
    #pragma unroll
    for (int off = 32; off >= 1; off >>= 1) { den += __shfl_xor(den, off); kof += __shfl_xor(kof, off); }
    float rden = 1.f / den;
    float c = e * is2 * rden;
    if (lane == 0) koffs[m] = kof * rden;
    const unsigned* y32 = (const unsigned*)yb;
    float p0 = 0.f, p1 = 0.f;
    #pragma unroll
    for (int n = 0; n < 29; ++n) {
      float cn = __shfl(c, n);
      unsigned u = y32[n*64 + lane];
      p0 = fmaf(cn, bf2f(u & 0xffffu), p0);
      p1 = fmaf(cn, bf2f(u >> 16), p1);
    }
    At32[m*68 + lane] = (unsigned)f2bf(p0) | ((unsigned)f2bf(p1) << 16);
  }
  __syncthreads();

  const int lrow = lane & 15, quad = lane >> 4;
  const int n0 = wv * 32;
  const unsigned short* wpi = (const unsigned short*)(ws + WPI_OFF);
  f32x4 acc[2];
  acc[0] = (f32x4){0.f,0.f,0.f,0.f}; acc[1] = acc[0];
  #pragma unroll
  for (int ks = 0; ks < 4; ++ks) {
    bf16x8 A0 = *(const bf16x8*)&Atile[lrow*ATSTR + ks*32 + quad*8];
    bf16x8 Bq0 = *(const bf16x8*)&wpi[(size_t)(n0 + lrow)*128 + ks*32 + quad*8];
    bf16x8 Bq1 = *(const bf16x8*)&wpi[(size_t)(n0 + 16 + lrow)*128 + ks*32 + quad*8];
    acc[0] = __builtin_amdgcn_mfma_f32_16x16x32_bf16(A0, Bq0, acc[0], 0, 0, 0);
    acc[1] = __builtin_amdgcn_mfma_f32_16x16x32_bf16(A0, Bq1, acc[1], 0, 0, 0);
  }

  float* bn3 = ws + BN3_OFF + (size_t)(blockIdx.x & 31) * 256;
  #pragma unroll
  for (int nt = 0; nt < 2; ++nt) {
    int col = n0 + nt*16 + lrow;
    float cswp = ws[CSWP_OFF + col], bp = bpv[col];
    float s1c = 0.f, s2c = 0.f;
    #pragma unroll
    for (int i = 0; i < 4; ++i) {
      int m = quad*4 + i;
      float x3 = acc[nt][i] - koffs[m]*cswp + bp;
      ws[X3_OFF + (size_t)(b0 + m)*D_ + col] = x3;
      s1c += x3; s2c = fmaf(x3, x3, s2c);
    }
    s1c += __shfl_xor(s1c, 16); s1c += __shfl_xor(s1c, 32);
    s2c += __shfl_xor(s2c, 16); s2c += __shfl_xor(s2c, 32);
    if (quad == 0) {
      atomicAdd(&bn3[col*2+0], s1c);
      atomicAdd(&bn3[col*2+1], s2c);
    }
  }
}

/* K5: 16 b per block (grid 512). bn3 finalize in-block;
   h = prelu(bn3(x3)@Wm1 + bm1) (MFMA, M=16); logit -> sigmoid. */
__global__ __launch_bounds__(256) void k5_mlp(
    const float* __restrict__ bm1, const float* __restrict__ amlp,
    const float* __restrict__ Wm2, const float* __restrict__ bm2,
    float* __restrict__ ws, float* __restrict__ out)
{
  __shared__ unsigned short Atile[KB4*ATSTR];
  __shared__ float m3s[128], is3s[128], logit_s[KB4];
  const int tid = threadIdx.x, wv = tid >> 6, lane = tid & 63;
  const int b0 = blockIdx.x * KB4;

  if (tid < 128) {
    float s1 = 0.f, s2 = 0.f;
    #pragma unroll 4
    for (int s = 0; s < 32; ++s) {
      s1 += ws[BN3_OFF + s*256 + tid*2 + 0];
      s2 += ws[BN3_OFF + s*256 + tid*2 + 1];
    }
    const float inv = 1.f / (float)B_;
    float mean = s1 * inv, var = s2 * inv - mean * mean;
    m3s[tid] = mean; is3s[tid] = rsqrtf(var + EPSBN);
  }
  if (tid >= 128 && tid < 128 + KB4) logit_s[tid-128] = 0.f;
  __syncthreads();

  #pragma unroll
  for (int it = 0; it < 8; ++it) {
    int idx = tid + it*256;
    int row = idx >> 7, col = idx & 127;
    float v = (ws[X3_OFF + (size_t)(b0+row)*D_ + col] - m3s[col]) * is3s[col];
    Atile[row*ATSTR + col] = f2bf(v);
  }
  __syncthreads();

  const int lrow = lane & 15, quad = lane >> 4;
  const int n0 = wv * 32;
  const unsigned short* wmi = (const unsigned short*)(ws + WM1I_OFF);
  f32x4 acc[2];
  acc[0] = (f32x4){0.f,0.f,0.f,0.f}; acc[1] = acc[0];
  #pragma unroll
  for (int ks = 0; ks < 4; ++ks) {
    bf16x8 A0 = *(const bf16x8*)&Atile[lrow*ATSTR + ks*32 + quad*8];
    bf16x8 Bq0 = *(const bf16x8*)&wmi[(size_t)(n0 + lrow)*128 + ks*32 + quad*8];
    bf16x8 Bq1 = *(const bf16x8*)&wmi[(size_t)(n0 + 16 + lrow)*128 + ks*32 + quad*8];
    acc[0] = __builtin_amdgcn_mfma_f32_16x16x32_bf16(A0, Bq0, acc[0], 0, 0, 0);
    acc[1] = __builtin_amdgcn_mfma_f32_16x16x32_bf16(A0, Bq1, acc[1], 0, 0, 0);
  }

  const float am = amlp[0];
  float bmc[2], wm2c[2];
  #pragma unroll
  for (int nt = 0; nt < 2; ++nt) {
    int col = n0 + nt*16 + lrow;
    bmc[nt] = bm1[col]; wm2c[nt] = Wm2[col];
  }
  #pragma unroll
  for (int i = 0; i < 4; ++i) {
    float pm = 0.f;
    #pragma unroll
    for (int nt = 0; nt < 2; ++nt) {
      float h = acc[nt][i] + bmc[nt];
      h = (h >= 0.f) ? h : am*h;
      pm = fmaf(h, wm2c[nt], pm);
    }
    #pragma unroll
    for (int off = 8; off >= 1; off >>= 1) pm += __shfl_xor(pm, off);
    if (lrow == 0) atomicAdd(&logit_s[quad*4 + i], pm);
  }
  __syncthreads();
  if (tid < KB4) {
    float logit = logit_s[tid] + bm2[0];
    out[b0 + tid] = 1.f / (1.f + expf(-logit));
  }
}

extern "C" void kernel_launch(void* const* d_in, const int* in_sizes, int n_in,
                              void* d_out, int out_size, void* d_ws, size_t ws_size,
                              hipStream_t stream)
{
  (void)in_sizes; (void)n_in; (void)out_size; (void)ws_size;
  const float* X    = (const float*)d_in[0];
  const float* corr = (const float*)d_in[1];
  const float* wc1  = (const float*)d_in[2];
  const float* bc1  = (const float*)d_in[3];
  const float* wc2  = (const float*)d_in[4];
  const float* bc2  = (const float*)d_in[5];
  const float* wc3  = (const float*)d_in[6];
  const float* bc3  = (const float*)d_in[7];
  const float* acnn = (const float*)d_in[8];
  const float* Wg   = (const float*)d_in[9];
  const float* bg   = (const float*)d_in[10];
  const float* agnn = (const float*)d_in[11];
  const float* cent = (const float*)d_in[12];
  const float* hw   = (const float*)d_in[13];
  const float* Wp   = (const float*)d_in[14];
  const float* bp   = (const float*)d_in[15];
  const float* Wm1  = (const float*)d_in[16];
  const float* bm1  = (const float*)d_in[17];
  const float* amlp = (const float*)d_in[18];
  const float* Wm2  = (const float*)d_in[19];
  const float* bm2  = (const float*)d_in[20];
  float* ws  = (float*)d_ws;
  float* out = (float*)d_out;

  k0_setup<<<19, 256, 0, stream>>>(Wg, Wp, Wm1, cent, hw, ws);
  k1_conv_gemm<<<B_, 256, 0, stream>>>(X, wc1, bc1, wc2, bc2, wc3, bc3, acnn, ws);
  k2_bn1f<<<1, 64, 0, stream>>>(ws);
  k3_gnn<<<B_/2, 256, 0, stream>>>(corr, bg, agnn, ws);
  k4_pool<<<B_/KB4, 256, 0, stream>>>(bp, ws);
  k5_mlp<<<B_/KB4, 256, 0, stream>>>(bm1, amlp, Wm2, bm2, ws, out);
}